// Round 1
// baseline (1843.048 us; speedup 1.0000x reference)
//
#include <hip/hip_runtime.h>

#define NN 100000

// ---------------- degree / dinv ----------------

__global__ void deg_init_kernel(float* __restrict__ deg, int N) {
    int i = blockIdx.x * blockDim.x + threadIdx.x;
    if (i < N) deg[i] = 1.0f;  // self-loop
}

__global__ void deg_count_kernel(const int* __restrict__ ei, float* __restrict__ deg, int E) {
    int e = blockIdx.x * blockDim.x + threadIdx.x;
    if (e < E) atomicAdd(&deg[ei[E + e]], 1.0f);  // in-degree at col
}

__global__ void rsqrt_kernel(float* __restrict__ dinv, int N) {
    int i = blockIdx.x * blockDim.x + threadIdx.x;
    if (i < N) dinv[i] = rsqrtf(dinv[i]);
}

// ---------------- linear layers ----------------

// Y[n][0:64]  = latent[n]   @ W1   (64x64)
// Y[n][64:128]= condition[n]@ W2   (32x64)
__global__ __launch_bounds__(256) void linear1_kernel(
    const float* __restrict__ lat, const float* __restrict__ cond,
    const float* __restrict__ W1, const float* __restrict__ W2,
    float* __restrict__ C, int N) {
    const int NPB = 2;
    __shared__ float ls[NPB][64];
    __shared__ float cs[NPB][32];
    int node0 = blockIdx.x * NPB;
    for (int i = threadIdx.x; i < NPB * 64; i += 256) {
        int nl = i >> 6, k = i & 63, n = node0 + nl;
        ls[nl][k] = (n < N) ? lat[(size_t)n * 64 + k] : 0.f;
    }
    for (int i = threadIdx.x; i < NPB * 32; i += 256) {
        int nl = i >> 5, k = i & 31, n = node0 + nl;
        cs[nl][k] = (n < N) ? cond[(size_t)n * 32 + k] : 0.f;
    }
    __syncthreads();
    int nl = threadIdx.x >> 7;          // 0..1
    int f  = threadIdx.x & 127;         // wave-uniform branch below (f<64 per wave)
    int n  = node0 + nl;
    if (n < N) {
        float acc = 0.f;
        if (f < 64) {
            #pragma unroll 8
            for (int k = 0; k < 64; ++k) acc += ls[nl][k] * W1[k * 64 + f];
        } else {
            int fo = f - 64;
            #pragma unroll 8
            for (int k = 0; k < 32; ++k) acc += cs[nl][k] * W2[k * 64 + fo];
        }
        C[(size_t)n * 128 + f] = acc;
    }
}

// C[n][f] = sum_k X[n][k] * W[k][f]
template <int K, int F, int NPB>
__global__ __launch_bounds__(NPB * F) void linear_kernel(
    const float* __restrict__ X, const float* __restrict__ W,
    float* __restrict__ C, int N) {
    __shared__ float xs[NPB][K];
    int node0 = blockIdx.x * NPB;
    for (int i = threadIdx.x; i < NPB * K; i += NPB * F) {
        int nl = i / K, k = i % K, n = node0 + nl;
        xs[nl][k] = (n < N) ? X[(size_t)n * K + k] : 0.f;
    }
    __syncthreads();
    int nl = threadIdx.x / F;
    int f  = threadIdx.x % F;
    int n  = node0 + nl;
    if (n < N) {
        float acc = 0.f;
        #pragma unroll 8
        for (int k = 0; k < K; ++k) acc += xs[nl][k] * W[k * F + f];
        C[(size_t)n * F + f] = acc;
    }
}

// ---------------- aggregation ----------------

// out[n][f] = Y[n][f]*dinv[n]^2 + bias[f]    (self-loop + bias, zero-init)
__global__ void agg_init128_kernel(const float* __restrict__ Y, const float* __restrict__ dinv,
                                   const float* __restrict__ b1, const float* __restrict__ b2,
                                   float* __restrict__ out, int N) {
    int idx = blockIdx.x * blockDim.x + threadIdx.x;
    int n = idx >> 7, f = idx & 127;
    if (n < N) {
        float d = dinv[n];
        float bias = (f < 64) ? b1[f] : b2[f - 64];
        out[idx] = Y[idx] * d * d + bias;
    }
}

__global__ void agg_init64_kernel(const float* __restrict__ Y, const float* __restrict__ dinv,
                                  const float* __restrict__ b, float* __restrict__ out, int N) {
    int idx = blockIdx.x * blockDim.x + threadIdx.x;
    int n = idx >> 6, f = idx & 63;
    if (n < N) {
        float d = dinv[n];
        out[idx] = Y[idx] * d * d + b[f];
    }
}

// out[col][f] += Y[row][f] * dinv[row]*dinv[col]  over all edges
template <int F>
__global__ __launch_bounds__(256) void agg_edge_kernel(
    const float* __restrict__ Y, const float* __restrict__ dinv,
    const int* __restrict__ ei, float* __restrict__ out, int E) {
    int t = blockIdx.x * 256 + threadIdx.x;
    int e = t / F;
    int f = t % F;
    if (e < E) {
        int r = ei[e];
        int c = ei[E + e];
        float norm = dinv[r] * dinv[c];
        atomicAdd(&out[(size_t)c * F + f], Y[(size_t)r * F + f] * norm);
    }
}

// ---------------- launch ----------------

extern "C" void kernel_launch(void* const* d_in, const int* in_sizes, int n_in,
                              void* d_out, int out_size, void* d_ws, size_t ws_size,
                              hipStream_t stream) {
    const float* latent = (const float*)d_in[0];
    const float* cond   = (const float*)d_in[1];
    const int*   ei     = (const int*)d_in[2];
    const float* W1 = (const float*)d_in[3];
    const float* b1 = (const float*)d_in[4];
    const float* W2 = (const float*)d_in[5];
    const float* b2 = (const float*)d_in[6];
    const float* W3 = (const float*)d_in[7];
    const float* b3 = (const float*)d_in[8];
    const float* W4 = (const float*)d_in[9];
    const float* b4 = (const float*)d_in[10];
    float* out = (float*)d_out;

    const int N = in_sizes[0] / 64;     // 100000
    const int E = in_sizes[2] / 2;      // 1600000

    // workspace layout: dinv (N f32, padded to 512KB), A (N*128 f32), B (N*128 f32)
    float* dinv = (float*)d_ws;
    float* A = (float*)d_ws + (1 << 17);
    float* B = A + (size_t)N * 128;

    const int BS = 256;
    int gN   = (N + BS - 1) / BS;
    int gE   = (E + BS - 1) / BS;
    int gN128 = (N * 128 + BS - 1) / BS;
    int gN64  = (N * 64 + BS - 1) / BS;
    int gE128 = (E / (BS / 128));       // E*128/256
    int gE64  = (E / (BS / 64));        // E*64/256

    // degrees -> dinv
    deg_init_kernel<<<gN, BS, 0, stream>>>(dinv, N);
    deg_count_kernel<<<gE, BS, 0, stream>>>(ei, dinv, E);
    rsqrt_kernel<<<gN, BS, 0, stream>>>(dinv, N);

    // layer 1+2 fused: A = [lat@W1 | cond@W2];  B = Ahat*A + [b1|b2]
    linear1_kernel<<<(N + 1) / 2, BS, 0, stream>>>(latent, cond, W1, W2, A, N);
    agg_init128_kernel<<<gN128, BS, 0, stream>>>(A, dinv, b1, b2, B, N);
    agg_edge_kernel<128><<<gE128, BS, 0, stream>>>(A, dinv, ei, B, E);

    // layer 3: A = B@W3 (128->64); B = Ahat*A + b3
    linear_kernel<128, 64, 4><<<(N + 3) / 4, BS, 0, stream>>>(B, W3, A, N);
    agg_init64_kernel<<<gN64, BS, 0, stream>>>(A, dinv, b3, B, N);
    agg_edge_kernel<64><<<gE64, BS, 0, stream>>>(A, dinv, ei, B, E);

    // layer 4: A = B@W4 (64->64); out = Ahat*A + b4
    linear_kernel<64, 64, 4><<<(N + 3) / 4, BS, 0, stream>>>(B, W4, A, N);
    agg_init64_kernel<<<gN64, BS, 0, stream>>>(A, dinv, b4, out, N);
    agg_edge_kernel<64><<<gE64, BS, 0, stream>>>(A, dinv, ei, out, E);
}

// Round 2
// 862.168 us; speedup vs baseline: 2.1377x; 2.1377x over previous
//
#include <hip/hip_runtime.h>

// ---------------- utility ----------------

__global__ void zero_int_kernel(int* __restrict__ p, int n) {
    int i = blockIdx.x * blockDim.x + threadIdx.x;
    if (i < n) p[i] = 0;
}

// histogram of destination (col) indices
__global__ void hist_kernel(const int* __restrict__ ei, int* __restrict__ cnt, int E) {
    int e = blockIdx.x * blockDim.x + threadIdx.x;
    if (e < E) atomicAdd(&cnt[ei[E + e]], 1);
}

__global__ void dinv_kernel(const int* __restrict__ cnt, float* __restrict__ dinv, int N) {
    int i = blockIdx.x * blockDim.x + threadIdx.x;
    if (i < N) dinv[i] = rsqrtf((float)cnt[i] + 1.0f);  // +1 self loop
}

// ---------------- scan (exclusive offsets from counts) ----------------

// S1: per-block (1024) inclusive scan; off[i+1] = in-block inclusive; bsum[b] = block total
__global__ __launch_bounds__(1024) void scan1_kernel(const int* __restrict__ cnt,
                                                     int* __restrict__ off,
                                                     int* __restrict__ bsum, int N) {
    __shared__ int s[1024];
    int tid = threadIdx.x;
    int i = blockIdx.x * 1024 + tid;
    int x = (i < N) ? cnt[i] : 0;
    s[tid] = x;
    __syncthreads();
    for (int o = 1; o < 1024; o <<= 1) {
        int v = (tid >= o) ? s[tid - o] : 0;
        __syncthreads();
        s[tid] += v;
        __syncthreads();
    }
    if (i < N) off[i + 1] = s[tid];
    if (tid == 1023) bsum[blockIdx.x] = s[1023];
}

// S2: single block exclusive scan of block sums (nb <= 128)
__global__ __launch_bounds__(128) void scan2_kernel(int* __restrict__ bsum, int nb) {
    __shared__ int s[128];
    int tid = threadIdx.x;
    int x = (tid < nb) ? bsum[tid] : 0;
    s[tid] = x;
    __syncthreads();
    for (int o = 1; o < 128; o <<= 1) {
        int v = (tid >= o) ? s[tid - o] : 0;
        __syncthreads();
        s[tid] += v;
        __syncthreads();
    }
    if (tid < nb) bsum[tid] = s[tid] - x;  // exclusive
}

// S3: finalize offsets, write scatter cursors
__global__ void scan3_kernel(const int* __restrict__ cnt, int* __restrict__ off,
                             const int* __restrict__ bsum, int* __restrict__ cur, int N) {
    int i = blockIdx.x * blockDim.x + threadIdx.x;
    if (i < N) {
        int fin = off[i + 1] + bsum[i >> 10];
        off[i + 1] = fin;
        cur[i] = fin - cnt[i];  // exclusive start
        if (i == 0) off[0] = 0;
    }
}

// scatter: rows grouped by destination col
__global__ void scatter_kernel(const int* __restrict__ ei, int* __restrict__ cur,
                               int* __restrict__ rows, int E) {
    int e = blockIdx.x * blockDim.x + threadIdx.x;
    if (e < E) {
        int c = ei[E + e];
        int pos = atomicAdd(&cur[c], 1);
        rows[pos] = ei[e];
    }
}

__global__ void bias128_kernel(const float* __restrict__ b1, const float* __restrict__ b2,
                               float* __restrict__ bias) {
    int i = threadIdx.x;
    bias[i] = (i < 64) ? b1[i] : b2[i - 64];
}

// ---------------- linear layers (epilogue scales row by dinv[n]) ----------------

// Q[n][0:64] = latent[n]@W1 * dinv[n];  Q[n][64:128] = condition[n]@W2 * dinv[n]
__global__ __launch_bounds__(256) void linear1_kernel(
    const float* __restrict__ lat, const float* __restrict__ cond,
    const float* __restrict__ W1, const float* __restrict__ W2,
    const float* __restrict__ dinv, float* __restrict__ C, int N) {
    const int NPB = 2;
    __shared__ float ls[NPB][64];
    __shared__ float cs[NPB][32];
    int node0 = blockIdx.x * NPB;
    for (int i = threadIdx.x; i < NPB * 64; i += 256) {
        int nl = i >> 6, k = i & 63, n = node0 + nl;
        ls[nl][k] = (n < N) ? lat[(size_t)n * 64 + k] : 0.f;
    }
    for (int i = threadIdx.x; i < NPB * 32; i += 256) {
        int nl = i >> 5, k = i & 31, n = node0 + nl;
        cs[nl][k] = (n < N) ? cond[(size_t)n * 32 + k] : 0.f;
    }
    __syncthreads();
    int nl = threadIdx.x >> 7;
    int f  = threadIdx.x & 127;
    int n  = node0 + nl;
    if (n < N) {
        float acc = 0.f;
        if (f < 64) {
            #pragma unroll 8
            for (int k = 0; k < 64; ++k) acc += ls[nl][k] * W1[k * 64 + f];
        } else {
            int fo = f - 64;
            #pragma unroll 8
            for (int k = 0; k < 32; ++k) acc += cs[nl][k] * W2[k * 64 + fo];
        }
        C[(size_t)n * 128 + f] = acc * dinv[n];
    }
}

// C[n][f] = (sum_k X[n][k] * W[k][f]) * dinv[n]
template <int K, int F, int NPB>
__global__ __launch_bounds__(NPB * F) void linear_kernel(
    const float* __restrict__ X, const float* __restrict__ W,
    const float* __restrict__ dinv, float* __restrict__ C, int N) {
    __shared__ float xs[NPB][K];
    int node0 = blockIdx.x * NPB;
    for (int i = threadIdx.x; i < NPB * K; i += NPB * F) {
        int nl = i / K, k = i % K, n = node0 + nl;
        xs[nl][k] = (n < N) ? X[(size_t)n * K + k] : 0.f;
    }
    __syncthreads();
    int nl = threadIdx.x / F;
    int f  = threadIdx.x % F;
    int n  = node0 + nl;
    if (n < N) {
        float acc = 0.f;
        #pragma unroll 8
        for (int k = 0; k < K; ++k) acc += xs[nl][k] * W[k * F + f];
        C[(size_t)n * F + f] = acc * dinv[n];
    }
}

// ---------------- CSR aggregation ----------------
// out[c][f] = dinv[c] * ( Yp[c][f] + sum_{r in in(c)} Yp[r][f] ) + bias[f]
// one wave per node; lane covers F/64 consecutive floats

template <int F>
__global__ __launch_bounds__(256) void agg_csr_kernel(
    const float* __restrict__ Yp, const float* __restrict__ dinv,
    const int* __restrict__ off, const int* __restrict__ rows,
    const float* __restrict__ bias, float* __restrict__ out, int N) {
    constexpr int V = F / 64;
    int wave = threadIdx.x >> 6;
    int lane = threadIdx.x & 63;
    int node = blockIdx.x * 4 + wave;
    if (node >= N) return;
    int s = off[node], e = off[node + 1];

    if constexpr (V == 2) {
        const float2* y2 = (const float2*)(Yp + (size_t)node * F);
        float2 acc = y2[lane];                       // self term (pre-scaled)
        float2 acc1 = make_float2(0.f, 0.f);
        int j = s;
        for (; j + 2 <= e; j += 2) {
            int r0 = rows[j], r1 = rows[j + 1];
            float2 a = ((const float2*)(Yp + (size_t)r0 * F))[lane];
            float2 b = ((const float2*)(Yp + (size_t)r1 * F))[lane];
            acc.x += a.x; acc.y += a.y;
            acc1.x += b.x; acc1.y += b.y;
        }
        if (j < e) {
            int r0 = rows[j];
            float2 a = ((const float2*)(Yp + (size_t)r0 * F))[lane];
            acc.x += a.x; acc.y += a.y;
        }
        float d = dinv[node];
        float2 res;
        res.x = (acc.x + acc1.x) * d + bias[2 * lane];
        res.y = (acc.y + acc1.y) * d + bias[2 * lane + 1];
        ((float2*)(out + (size_t)node * F))[lane] = res;
    } else {
        const float* y = Yp + (size_t)node * F;
        float acc = y[lane];
        float acc1 = 0.f;
        int j = s;
        for (; j + 2 <= e; j += 2) {
            int r0 = rows[j], r1 = rows[j + 1];
            acc  += Yp[(size_t)r0 * F + lane];
            acc1 += Yp[(size_t)r1 * F + lane];
        }
        if (j < e) acc += Yp[(size_t)rows[j] * F + lane];
        float d = dinv[node];
        out[(size_t)node * F + lane] = (acc + acc1) * d + bias[lane];
    }
}

// ---------------- launch ----------------

static inline size_t align256(size_t x) { return (x + 255) & ~(size_t)255; }

extern "C" void kernel_launch(void* const* d_in, const int* in_sizes, int n_in,
                              void* d_out, int out_size, void* d_ws, size_t ws_size,
                              hipStream_t stream) {
    const float* latent = (const float*)d_in[0];
    const float* cond   = (const float*)d_in[1];
    const int*   ei     = (const int*)d_in[2];
    const float* W1 = (const float*)d_in[3];
    const float* b1 = (const float*)d_in[4];
    const float* W2 = (const float*)d_in[5];
    const float* b2 = (const float*)d_in[6];
    const float* W3 = (const float*)d_in[7];
    const float* b3 = (const float*)d_in[8];
    const float* W4 = (const float*)d_in[9];
    const float* b4 = (const float*)d_in[10];
    float* out = (float*)d_out;

    const int N = in_sizes[0] / 64;     // 100000
    const int E = in_sizes[2] / 2;      // 1600000

    // workspace layout
    char* w = (char*)d_ws;
    size_t o = 0;
    int* cnt   = (int*)(w + o); o = align256(o + (size_t)N * 4);
    int* off   = (int*)(w + o); o = align256(o + (size_t)(N + 1) * 4);
    int* cur   = (int*)(w + o); o = align256(o + (size_t)N * 4);
    int* bsum  = (int*)(w + o); o = align256(o + 128 * 4);
    float* bias128 = (float*)(w + o); o = align256(o + 128 * 4);
    float* dinv = (float*)(w + o); o = align256(o + (size_t)N * 4);
    int* rows  = (int*)(w + o); o = align256(o + (size_t)E * 4);
    float* Q = (float*)(w + o); o = align256(o + (size_t)N * 128 * 4);   // linear out (pre-scaled)
    float* P = (float*)(w + o); o = align256(o + (size_t)N * 128 * 4);   // agg out

    const int BS = 256;
    int gN  = (N + BS - 1) / BS;
    int gE  = (E + BS - 1) / BS;
    int nb  = (N + 1023) / 1024;
    int gAgg = (N + 3) / 4;

    // ---- CSR build + dinv ----
    zero_int_kernel<<<gN, BS, 0, stream>>>(cnt, N);
    hist_kernel<<<gE, BS, 0, stream>>>(ei, cnt, E);
    dinv_kernel<<<gN, BS, 0, stream>>>(cnt, dinv, N);
    scan1_kernel<<<nb, 1024, 0, stream>>>(cnt, off, bsum, N);
    scan2_kernel<<<1, 128, 0, stream>>>(bsum, nb);
    scan3_kernel<<<gN, BS, 0, stream>>>(cnt, off, bsum, cur, N);
    scatter_kernel<<<gE, BS, 0, stream>>>(ei, cur, rows, E);
    bias128_kernel<<<1, 128, 0, stream>>>(b1, b2, bias128);

    // ---- layer 1+2 fused: Q = [lat@W1 | cond@W2]*dinv;  P = agg(Q) ----
    linear1_kernel<<<(N + 1) / 2, BS, 0, stream>>>(latent, cond, W1, W2, dinv, Q, N);
    agg_csr_kernel<128><<<gAgg, BS, 0, stream>>>(Q, dinv, off, rows, bias128, P, N);

    // ---- layer 3: Q64 = P@W3*dinv; P64 = agg(Q64) ----
    linear_kernel<128, 64, 4><<<(N + 3) / 4, BS, 0, stream>>>(P, W3, dinv, Q, N);
    agg_csr_kernel<64><<<gAgg, BS, 0, stream>>>(Q, dinv, off, rows, b3, P, N);

    // ---- layer 4: Q64 = P64@W4*dinv; out = agg(Q64) ----
    linear_kernel<64, 64, 4><<<(N + 3) / 4, BS, 0, stream>>>(P, W4, dinv, Q, N);
    agg_csr_kernel<64><<<gAgg, BS, 0, stream>>>(Q, dinv, off, rows, b4, out, N);
}

// Round 3
// 756.231 us; speedup vs baseline: 2.4371x; 1.1401x over previous
//
#include <hip/hip_runtime.h>

// ---------------- utility ----------------

__global__ void zero_int_kernel(int* __restrict__ p, int n) {
    int i = blockIdx.x * blockDim.x + threadIdx.x;
    if (i < n) p[i] = 0;
}

// histogram of destination (col) indices
__global__ void hist_kernel(const int* __restrict__ ei, int* __restrict__ cnt, int E) {
    int e = blockIdx.x * blockDim.x + threadIdx.x;
    if (e < E) atomicAdd(&cnt[ei[E + e]], 1);
}

__global__ void dinv_kernel(const int* __restrict__ cnt, float* __restrict__ dinv, int N) {
    int i = blockIdx.x * blockDim.x + threadIdx.x;
    if (i < N) dinv[i] = rsqrtf((float)cnt[i] + 1.0f);  // +1 self loop
}

// ---------------- scan (exclusive offsets from counts) ----------------

__global__ __launch_bounds__(1024) void scan1_kernel(const int* __restrict__ cnt,
                                                     int* __restrict__ off,
                                                     int* __restrict__ bsum, int N) {
    __shared__ int s[1024];
    int tid = threadIdx.x;
    int i = blockIdx.x * 1024 + tid;
    int x = (i < N) ? cnt[i] : 0;
    s[tid] = x;
    __syncthreads();
    for (int o = 1; o < 1024; o <<= 1) {
        int v = (tid >= o) ? s[tid - o] : 0;
        __syncthreads();
        s[tid] += v;
        __syncthreads();
    }
    if (i < N) off[i + 1] = s[tid];
    if (tid == 1023) bsum[blockIdx.x] = s[1023];
}

__global__ __launch_bounds__(128) void scan2_kernel(int* __restrict__ bsum, int nb) {
    __shared__ int s[128];
    int tid = threadIdx.x;
    int x = (tid < nb) ? bsum[tid] : 0;
    s[tid] = x;
    __syncthreads();
    for (int o = 1; o < 128; o <<= 1) {
        int v = (tid >= o) ? s[tid - o] : 0;
        __syncthreads();
        s[tid] += v;
        __syncthreads();
    }
    if (tid < nb) bsum[tid] = s[tid] - x;  // exclusive
}

__global__ void scan3_kernel(const int* __restrict__ cnt, int* __restrict__ off,
                             const int* __restrict__ bsum, int* __restrict__ cur, int N) {
    int i = blockIdx.x * blockDim.x + threadIdx.x;
    if (i < N) {
        int fin = off[i + 1] + bsum[i >> 10];
        off[i + 1] = fin;
        cur[i] = fin - cnt[i];
        if (i == 0) off[0] = 0;
    }
}

__global__ void scatter_kernel(const int* __restrict__ ei, int* __restrict__ cur,
                               int* __restrict__ rows, int E) {
    int e = blockIdx.x * blockDim.x + threadIdx.x;
    if (e < E) {
        int c = ei[E + e];
        int pos = atomicAdd(&cur[c], 1);
        rows[pos] = ei[e];
    }
}

// ---------------- weight folding ----------------
// Wf1 = W1 * (W3[0:64,:] * W4)       [64x64]
// Wf2 = W2 * (W3[64:128,:] * W4)     [32x64]
// u   = (b12 * W3) * W4              [64]
// v   = b3 * W4                      [64]
__global__ __launch_bounds__(256) void fold_kernel(
    const float* __restrict__ W1, const float* __restrict__ b1,
    const float* __restrict__ W2, const float* __restrict__ b2,
    const float* __restrict__ W3, const float* __restrict__ b3,
    const float* __restrict__ W4,
    float* __restrict__ Wf1, float* __restrict__ Wf2,
    float* __restrict__ u, float* __restrict__ v) {
    __shared__ float A1[64][64];   // W3top*W4
    __shared__ float A2[64][64];   // W3bot*W4
    __shared__ float gs[64];       // b12*W3
    int q = threadIdx.x >> 6;      // 0..3
    int f = threadIdx.x & 63;
    // step 1: A1,A2
    for (int i = q * 16; i < q * 16 + 16; ++i) {
        float a1 = 0.f, a2 = 0.f;
        for (int k = 0; k < 64; ++k) {
            float w4 = W4[k * 64 + f];
            a1 += W3[i * 64 + k] * w4;
            a2 += W3[(64 + i) * 64 + k] * w4;
        }
        A1[i][f] = a1;
        A2[i][f] = a2;
    }
    if (q == 0) {
        float g = 0.f;
        for (int k = 0; k < 64; ++k) g += b1[k] * W3[k * 64 + f];
        for (int k = 0; k < 64; ++k) g += b2[k] * W3[(64 + k) * 64 + f];
        gs[f] = g;
    }
    __syncthreads();
    // step 2: Wf1, Wf2
    for (int i = q * 16; i < q * 16 + 16; ++i) {
        float a = 0.f;
        for (int k = 0; k < 64; ++k) a += W1[i * 64 + k] * A1[k][f];
        Wf1[i * 64 + f] = a;
    }
    for (int i = q * 8; i < q * 8 + 8; ++i) {
        float a = 0.f;
        for (int k = 0; k < 64; ++k) a += W2[i * 64 + k] * A2[k][f];
        Wf2[i * 64 + f] = a;
    }
    if (q == 0) {
        float uu = 0.f, vv = 0.f;
        for (int k = 0; k < 64; ++k) {
            uu += gs[k] * W4[k * 64 + f];
            vv += b3[k] * W4[k * 64 + f];
        }
        u[f] = uu;
        v[f] = vv;
    }
}

// ---------------- fused linear: Z[n] = (lat[n]@Wf1 + cond[n]@Wf2) * dinv[n] ----------------
__global__ __launch_bounds__(256) void linZ_kernel(
    const float* __restrict__ lat, const float* __restrict__ cond,
    const float* __restrict__ Wf1, const float* __restrict__ Wf2,
    const float* __restrict__ dinv, float* __restrict__ Z, int N) {
    const int NPB = 4;
    __shared__ float ls[NPB][64];
    __shared__ float cs[NPB][32];
    int node0 = blockIdx.x * NPB;
    {
        int i = threadIdx.x;                 // 256 = 4*64 exactly
        int nl = i >> 6, k = i & 63, n = node0 + nl;
        ls[nl][k] = (n < N) ? lat[(size_t)n * 64 + k] : 0.f;
        if (i < NPB * 32) {
            int nl2 = i >> 5, k2 = i & 31, n2 = node0 + nl2;
            cs[nl2][k2] = (n2 < N) ? cond[(size_t)n2 * 32 + k2] : 0.f;
        }
    }
    __syncthreads();
    int nl = threadIdx.x >> 6;
    int f  = threadIdx.x & 63;
    int n  = node0 + nl;
    if (n < N) {
        float acc = 0.f;
        #pragma unroll 8
        for (int k = 0; k < 64; ++k) acc += ls[nl][k] * Wf1[k * 64 + f];
        #pragma unroll 8
        for (int k = 0; k < 32; ++k) acc += cs[nl][k] * Wf2[k * 64 + f];
        Z[(size_t)n * 64 + f] = acc * dinv[n];
    }
}

// ---------------- scalar aggregations: s = A_hat * 1, t = A_hat * s ----------------
__global__ void s_kernel(const float* __restrict__ dinv, const int* __restrict__ off,
                         const int* __restrict__ rows, float* __restrict__ sArr,
                         float* __restrict__ spArr, int N) {
    int i = blockIdx.x * blockDim.x + threadIdx.x;
    if (i >= N) return;
    float d = dinv[i];
    float a = d;
    int e1 = off[i + 1];
    for (int j = off[i]; j < e1; ++j) a += dinv[rows[j]];
    sArr[i] = d * a;
    spArr[i] = d * d * a;   // dinv * s
}

__global__ void t_kernel(const float* __restrict__ dinv, const int* __restrict__ off,
                         const int* __restrict__ rows, const float* __restrict__ spArr,
                         float* __restrict__ tArr, int N) {
    int i = blockIdx.x * blockDim.x + threadIdx.x;
    if (i >= N) return;
    float d = dinv[i];
    float a = spArr[i];
    int e1 = off[i + 1];
    for (int j = off[i]; j < e1; ++j) a += spArr[rows[j]];
    tArr[i] = d * a;
}

// ---------------- CSR aggregation, F=64, wave per node ----------------
// input V' rows pre-scaled by dinv. acc = V'[c] + sum_in V'[r].
// FINAL=false: out[c] = acc * dinv[c]^2         (stay pre-scaled for next hop)
// FINAL=true : out[c] = acc * dinv[c] + t[c]*u + s[c]*v + b4
template <bool FINAL>
__global__ __launch_bounds__(256) void agg64_kernel(
    const float* __restrict__ Vp, const float* __restrict__ dinv,
    const int* __restrict__ off, const int* __restrict__ rows,
    const float* __restrict__ sArr, const float* __restrict__ tArr,
    const float* __restrict__ u, const float* __restrict__ v,
    const float* __restrict__ b4, float* __restrict__ out, int N) {
    int wave = threadIdx.x >> 6;
    int lane = threadIdx.x & 63;
    int node = blockIdx.x * 4 + wave;
    if (node >= N) return;
    int s = off[node], e = off[node + 1];

    float acc = Vp[(size_t)node * 64 + lane];
    float acc1 = 0.f;
    int j = s;
    for (; j + 2 <= e; j += 2) {
        int r0 = rows[j], r1 = rows[j + 1];
        acc  += Vp[(size_t)r0 * 64 + lane];
        acc1 += Vp[(size_t)r1 * 64 + lane];
    }
    if (j < e) acc += Vp[(size_t)rows[j] * 64 + lane];
    float d = dinv[node];
    float r = (acc + acc1);
    if constexpr (FINAL) {
        out[(size_t)node * 64 + lane] =
            r * d + tArr[node] * u[lane] + sArr[node] * v[lane] + b4[lane];
    } else {
        out[(size_t)node * 64 + lane] = r * d * d;
    }
}

// ---------------- launch ----------------

static inline size_t align256(size_t x) { return (x + 255) & ~(size_t)255; }

extern "C" void kernel_launch(void* const* d_in, const int* in_sizes, int n_in,
                              void* d_out, int out_size, void* d_ws, size_t ws_size,
                              hipStream_t stream) {
    const float* latent = (const float*)d_in[0];
    const float* cond   = (const float*)d_in[1];
    const int*   ei     = (const int*)d_in[2];
    const float* W1 = (const float*)d_in[3];
    const float* b1 = (const float*)d_in[4];
    const float* W2 = (const float*)d_in[5];
    const float* b2 = (const float*)d_in[6];
    const float* W3 = (const float*)d_in[7];
    const float* b3 = (const float*)d_in[8];
    const float* W4 = (const float*)d_in[9];
    const float* b4 = (const float*)d_in[10];
    float* out = (float*)d_out;

    const int N = in_sizes[0] / 64;     // 100000
    const int E = in_sizes[2] / 2;      // 1600000

    // workspace layout
    char* w = (char*)d_ws;
    size_t o = 0;
    int* cnt   = (int*)(w + o); o = align256(o + (size_t)N * 4);
    int* off   = (int*)(w + o); o = align256(o + (size_t)(N + 1) * 4);
    int* cur   = (int*)(w + o); o = align256(o + (size_t)N * 4);
    int* bsum  = (int*)(w + o); o = align256(o + 128 * 4);
    float* dinv = (float*)(w + o); o = align256(o + (size_t)N * 4);
    float* sArr = (float*)(w + o); o = align256(o + (size_t)N * 4);
    float* spArr = (float*)(w + o); o = align256(o + (size_t)N * 4);
    float* tArr = (float*)(w + o); o = align256(o + (size_t)N * 4);
    float* Wf1 = (float*)(w + o); o = align256(o + 4096 * 4);
    float* Wf2 = (float*)(w + o); o = align256(o + 2048 * 4);
    float* uVec = (float*)(w + o); o = align256(o + 64 * 4);
    float* vVec = (float*)(w + o); o = align256(o + 64 * 4);
    int* rows  = (int*)(w + o); o = align256(o + (size_t)E * 4);
    float* Z = (float*)(w + o); o = align256(o + (size_t)N * 64 * 4);
    float* P = (float*)(w + o); o = align256(o + (size_t)N * 64 * 4);

    const int BS = 256;
    int gN  = (N + BS - 1) / BS;
    int gE  = (E + BS - 1) / BS;
    int nb  = (N + 1023) / 1024;
    int gAgg = (N + 3) / 4;

    // ---- CSR build + dinv ----
    zero_int_kernel<<<gN, BS, 0, stream>>>(cnt, N);
    hist_kernel<<<gE, BS, 0, stream>>>(ei, cnt, E);
    dinv_kernel<<<gN, BS, 0, stream>>>(cnt, dinv, N);
    scan1_kernel<<<nb, 1024, 0, stream>>>(cnt, off, bsum, N);
    scan2_kernel<<<1, 128, 0, stream>>>(bsum, nb);
    scan3_kernel<<<gN, BS, 0, stream>>>(cnt, off, bsum, cur, N);
    scatter_kernel<<<gE, BS, 0, stream>>>(ei, cur, rows, E);

    // ---- weight fold + fused linear ----
    fold_kernel<<<1, 256, 0, stream>>>(W1, b1, W2, b2, W3, b3, W4, Wf1, Wf2, uVec, vVec);
    linZ_kernel<<<(N + 3) / 4, BS, 0, stream>>>(latent, cond, Wf1, Wf2, dinv, Z, N);

    // ---- scalar aggregations s = A1, t = As ----
    s_kernel<<<gN, BS, 0, stream>>>(dinv, off, rows, sArr, spArr, N);
    t_kernel<<<gN, BS, 0, stream>>>(dinv, off, rows, spArr, tArr, N);

    // ---- three aggregation hops ----
    agg64_kernel<false><<<gAgg, BS, 0, stream>>>(Z, dinv, off, rows, nullptr, nullptr,
                                                 nullptr, nullptr, nullptr, P, N);
    agg64_kernel<false><<<gAgg, BS, 0, stream>>>(P, dinv, off, rows, nullptr, nullptr,
                                                 nullptr, nullptr, nullptr, Z, N);
    agg64_kernel<true><<<gAgg, BS, 0, stream>>>(Z, dinv, off, rows, sArr, tArr,
                                                uVec, vVec, b4, out, N);
}